// Round 5
// baseline (42991.647 us; speedup 1.0000x reference)
//
#include <hip/hip_runtime.h>
#include <hip/hip_bf16.h>
#include <hip/hip_cooperative_groups.h>

namespace cg = cooperative_groups;

static constexpr int T_ = 512, B_ = 128, DIM_ = 512, H_ = 1024, OUT_ = 512;
static constexpr size_t BH = (size_t)B_ * H_;

__global__ void copy_h0_kernel(const float* __restrict__ h0, float* __restrict__ out) {
    int i = blockIdx.x * blockDim.x + threadIdx.x;
    if (i < B_ * H_) out[i] = h0[i];
}

// C[M,N] = act( A[M,K] @ W[N,K]^T + biases )
// NB: 0=none, 1=+b1[c], 2=+b1[c]+b2[c];  ACT: 0=id, 1=tanh, 2=sigmoid
template<int BM, int BN, int BK, int TM, int TN, int NB, int ACT>
__launch_bounds__((BM/TM)*(BN/TN))
__global__ void gemm_kernel(const float* __restrict__ A, const float* __restrict__ W,
                            const float* __restrict__ b1, const float* __restrict__ b2,
                            float* __restrict__ outp, int M, int N, int K)
{
    constexpr int NT = (BM/TM)*(BN/TN);
    __shared__ float As[BK][BM+8];
    __shared__ float Ws[BK][BN+8];
    const int tid  = threadIdx.x;
    const int col0 = blockIdx.x * BN;
    const int row0 = blockIdx.y * BM;
    const int tx = tid % (BN/TN);
    const int ty = tid / (BN/TN);
    const int n0 = tx * TN, m0 = ty * TM;

    float acc[TM][TN];
    #pragma unroll
    for (int i = 0; i < TM; ++i)
        #pragma unroll
        for (int j = 0; j < TN; ++j) acc[i][j] = 0.f;

    for (int k0 = 0; k0 < K; k0 += BK) {
        for (int i = tid; i < BM*BK/4; i += NT) {
            const int r  = i / (BK/4);
            const int kc = (i % (BK/4)) * 4;
            const float* s = A + (size_t)(row0 + r) * K + (k0 + kc);
            #pragma unroll
            for (int j = 0; j < 4; ++j) As[kc + j][r] = s[j];
        }
        for (int i = tid; i < BN*BK/4; i += NT) {
            const int r  = i / (BK/4);
            const int kc = (i % (BK/4)) * 4;
            const float* s = W + (size_t)(col0 + r) * K + (k0 + kc);
            #pragma unroll
            for (int j = 0; j < 4; ++j) Ws[kc + j][r] = s[j];
        }
        __syncthreads();
        #pragma unroll
        for (int k = 0; k < BK; ++k) {
            float av[TM], wv[TN];
            if constexpr (TM == 8) {
                *(float4*)&av[0] = *(const float4*)&As[k][m0];
                *(float4*)&av[4] = *(const float4*)&As[k][m0+4];
            } else {
                #pragma unroll
                for (int i = 0; i < TM; ++i) av[i] = As[k][m0 + i];
            }
            if constexpr (TN == 8) {
                *(float4*)&wv[0] = *(const float4*)&Ws[k][n0];
                *(float4*)&wv[4] = *(const float4*)&Ws[k][n0+4];
            } else {
                #pragma unroll
                for (int j = 0; j < TN; ++j) wv[j] = Ws[k][n0 + j];
            }
            #pragma unroll
            for (int i = 0; i < TM; ++i)
                #pragma unroll
                for (int j = 0; j < TN; ++j) acc[i][j] = fmaf(av[i], wv[j], acc[i][j]);
        }
        __syncthreads();
    }

    #pragma unroll
    for (int i = 0; i < TM; ++i) {
        const size_t r = (size_t)(row0 + m0 + i);
        #pragma unroll
        for (int j = 0; j < TN; ++j) {
            const int c = col0 + n0 + j;
            float v = acc[i][j];
            if constexpr (NB >= 1) v += b1[c];
            if constexpr (NB >= 2) v += b2[c];
            if constexpr (ACT == 1) v = tanhf(v);
            else if constexpr (ACT == 2) v = 1.0f / (1.0f + expf(-v));
            outp[r * (size_t)N + c] = v;
        }
    }
}

// ---------------- persistent cooperative recurrence ----------------
// 256 blocks x 512 threads (1 block/CU). Block owns a [16 rows x 32 cols]
// output tile; its Wh slice (32x1024 f32 = 128KB) staged in LDS ONCE
// (swizzled, +pad) and reused for all 512 steps. 8 waves k-split (128 k),
// lane = (rg, cg, kh): 4x4 register blocking -> 8 FMA per b128 operand load.
// Per step: per-lane global h reads (L1/L3-hot), LDS-broadcast Wh,
// shfl kh-fold, LDS cross-wave reduce, fused xp+tanh, grid.sync().
static constexpr int RB = 16, CB = 32, WPAD = 1028;

__device__ __forceinline__ int wh_off(int j, int k) {
    return j * WPAD + (k ^ (((k >> 6) & 1) << 2));
}

__global__ __launch_bounds__(512, 1)
void rnn_persistent(const float* __restrict__ Wh, float* __restrict__ all_h)
{
    __shared__ float WhS[CB * WPAD];        // 131.6 KB, swizzled
    __shared__ float red[RB * CB][8];       // 16 KB

    const int tid = threadIdx.x;
    const int blk = blockIdx.x;
    const int r0  = (blk >> 5) * RB;        // 8 row-blocks
    const int c0  = (blk & 31) * CB;        // 32 col-blocks

    // One-time Wh stage: 32 rows (cols c0..c0+31) x 1024 k.
    for (int it = 0; it < 16; ++it) {
        const int c  = tid + it * 512;       // f4 chunk id, 8192 total
        const int j  = c >> 8;
        const int kc = (c & 255) * 4;
        const float4 v = *(const float4*)(Wh + (size_t)(c0 + j) * H_ + kc);
        *(float4*)(WhS + wh_off(j, kc)) = v;
    }
    __syncthreads();

    const int w    = tid >> 6;              // wave: k-range [w*128, +128)
    const int lane = tid & 63;
    const int rg   = lane & 3;              // rows rg*4..+3
    const int cgp  = (lane >> 2) & 7;       // cols cgp*4..+3
    const int kh   = lane >> 5;             // k-sub [*, +64)
    const int kbase = w * 128 + kh * 64;

    const int ep_r = tid >> 5, ep_c = tid & 31;
    const size_t ep_idx = (size_t)(r0 + ep_r) * H_ + (c0 + ep_c);

    cg::grid_group grid = cg::this_grid();

    for (int t = 0; t < T_; ++t) {
        const float* __restrict__ hsrc = all_h + (size_t)t * BH;
        float* __restrict__ hdst = all_h + (size_t)(t + 1) * BH;

        const float xpv = hdst[ep_idx];     // staged xp, prefetch early

        float acc[4][4];
        #pragma unroll
        for (int i = 0; i < 4; ++i)
            #pragma unroll
            for (int j = 0; j < 4; ++j) acc[i][j] = 0.f;

        const float* hb = hsrc + (size_t)(r0 + rg * 4) * H_ + kbase;

        #pragma unroll 2
        for (int kg = 0; kg < 16; ++kg) {
            float4 hv[4];
            #pragma unroll
            for (int i = 0; i < 4; ++i)
                hv[i] = *(const float4*)(hb + (size_t)i * H_ + kg * 4);
            float4 wv[4];
            const int k = kbase + kg * 4;
            #pragma unroll
            for (int j = 0; j < 4; ++j)
                wv[j] = *(const float4*)(WhS + wh_off(cgp * 4 + j, k));
            #pragma unroll
            for (int i = 0; i < 4; ++i) {
                #pragma unroll
                for (int j = 0; j < 4; ++j) {
                    acc[i][j] = fmaf(hv[i].x, wv[j].x, acc[i][j]);
                    acc[i][j] = fmaf(hv[i].y, wv[j].y, acc[i][j]);
                    acc[i][j] = fmaf(hv[i].z, wv[j].z, acc[i][j]);
                    acc[i][j] = fmaf(hv[i].w, wv[j].w, acc[i][j]);
                }
            }
        }

        // fold the two k-halves within the wave
        #pragma unroll
        for (int i = 0; i < 4; ++i)
            #pragma unroll
            for (int j = 0; j < 4; ++j)
                acc[i][j] += __shfl_xor(acc[i][j], 32, 64);

        if (kh == 0) {
            #pragma unroll
            for (int i = 0; i < 4; ++i)
                #pragma unroll
                for (int j = 0; j < 4; ++j)
                    red[(rg * 4 + i) * CB + cgp * 4 + j][w] = acc[i][j];
        }
        __syncthreads();

        // epilogue: 512 threads, 1 cell each
        {
            const float4 p0 = *(const float4*)&red[tid][0];
            const float4 p1 = *(const float4*)&red[tid][4];
            const float s = ((p0.x + p0.y) + (p0.z + p0.w))
                          + ((p1.x + p1.y) + (p1.z + p1.w));
            hdst[ep_idx] = tanhf(s + xpv);
        }
        __threadfence();
        grid.sync();
    }
}

extern "C" void kernel_launch(void* const* d_in, const int* in_sizes, int n_in,
                              void* d_out, int out_size, void* d_ws, size_t ws_size,
                              hipStream_t stream)
{
    const float* x    = (const float*)d_in[0];
    const float* h0   = (const float*)d_in[1];
    const float* Wx_w = (const float*)d_in[2];
    const float* Wx_b = (const float*)d_in[3];
    const float* Wh_w = (const float*)d_in[4];
    const float* Wh_b = (const float*)d_in[5];
    const float* Wo_w = (const float*)d_in[6];
    const float* Wo_b = (const float*)d_in[7];

    float* out   = (float*)d_out;
    float* all_h = out;                              // [T+1][B][H]
    float* all_y = out + (size_t)(T_ + 1) * BH;      // [T][B][OUT]
    float* last  = all_y + (size_t)T_ * B_ * OUT_;   // [B][OUT]

    // all_h[0] = h0
    copy_h0_kernel<<<dim3((B_*H_ + 255)/256), dim3(256), 0, stream>>>(h0, all_h);

    // Stage xproj = x@Wx^T + Wx_b + Wh_b into all_h[1..T]
    gemm_kernel<128, 128, 16, 8, 8, 2, 0>
        <<<dim3(H_/128, (T_*B_)/128), dim3(256), 0, stream>>>(
            x, Wx_w, Wx_b, Wh_b, all_h + BH, T_*B_, H_, DIM_);

    // Whole recurrence in ONE cooperative launch.
    {
        const float* whp = Wh_w;
        float* ahp = all_h;
        void* args[] = { (void*)&whp, (void*)&ahp };
        hipLaunchCooperativeKernel((const void*)rnn_persistent,
                                   dim3(256), dim3(512), args, 0, stream);
    }

    // all_y = sigmoid(hs @ Wo^T + Wo_b)
    gemm_kernel<128, 128, 16, 8, 8, 1, 2>
        <<<dim3(OUT_/128, (T_*B_)/128), dim3(256), 0, stream>>>(
            all_h + BH, Wo_w, Wo_b, nullptr, all_y, T_*B_, OUT_, H_);

    // last_logits = h_T @ Wo^T + Wo_b
    gemm_kernel<16, 64, 32, 1, 4, 1, 0>
        <<<dim3(OUT_/64, B_/16), dim3(256), 0, stream>>>(
            all_h + (size_t)T_ * BH, Wo_w, Wo_b, nullptr, last, B_, OUT_, H_);
}

// Round 6
// 6883.144 us; speedup vs baseline: 6.2459x; 6.2459x over previous
//
#include <hip/hip_runtime.h>
#include <hip/hip_bf16.h>

static constexpr int T_ = 512, B_ = 128, DIM_ = 512, H_ = 1024, OUT_ = 512;
static constexpr size_t BH = (size_t)B_ * H_;

__global__ void copy_h0_kernel(const float* __restrict__ h0, float* __restrict__ out) {
    int i = blockIdx.x * blockDim.x + threadIdx.x;
    if (i < B_ * H_) out[i] = h0[i];
}

// C[M,N] = act( A[M,K] @ W[N,K]^T + biases )
// NB: 0=none, 1=+b1[c], 2=+b1[c]+b2[c];  ACT: 0=id, 1=tanh, 2=sigmoid
template<int BM, int BN, int BK, int TM, int TN, int NB, int ACT>
__launch_bounds__((BM/TM)*(BN/TN))
__global__ void gemm_kernel(const float* __restrict__ A, const float* __restrict__ W,
                            const float* __restrict__ b1, const float* __restrict__ b2,
                            float* __restrict__ outp, int M, int N, int K)
{
    constexpr int NT = (BM/TM)*(BN/TN);
    __shared__ float As[BK][BM+8];
    __shared__ float Ws[BK][BN+8];
    const int tid  = threadIdx.x;
    const int col0 = blockIdx.x * BN;
    const int row0 = blockIdx.y * BM;
    const int tx = tid % (BN/TN);
    const int ty = tid / (BN/TN);
    const int n0 = tx * TN, m0 = ty * TM;

    float acc[TM][TN];
    #pragma unroll
    for (int i = 0; i < TM; ++i)
        #pragma unroll
        for (int j = 0; j < TN; ++j) acc[i][j] = 0.f;

    for (int k0 = 0; k0 < K; k0 += BK) {
        for (int i = tid; i < BM*BK/4; i += NT) {
            const int r  = i / (BK/4);
            const int kc = (i % (BK/4)) * 4;
            const float* s = A + (size_t)(row0 + r) * K + (k0 + kc);
            #pragma unroll
            for (int j = 0; j < 4; ++j) As[kc + j][r] = s[j];
        }
        for (int i = tid; i < BN*BK/4; i += NT) {
            const int r  = i / (BK/4);
            const int kc = (i % (BK/4)) * 4;
            const float* s = W + (size_t)(col0 + r) * K + (k0 + kc);
            #pragma unroll
            for (int j = 0; j < 4; ++j) Ws[kc + j][r] = s[j];
        }
        __syncthreads();
        #pragma unroll
        for (int k = 0; k < BK; ++k) {
            float av[TM], wv[TN];
            if constexpr (TM == 8) {
                *(float4*)&av[0] = *(const float4*)&As[k][m0];
                *(float4*)&av[4] = *(const float4*)&As[k][m0+4];
            } else {
                #pragma unroll
                for (int i = 0; i < TM; ++i) av[i] = As[k][m0 + i];
            }
            if constexpr (TN == 8) {
                *(float4*)&wv[0] = *(const float4*)&Ws[k][n0];
                *(float4*)&wv[4] = *(const float4*)&Ws[k][n0+4];
            } else {
                #pragma unroll
                for (int j = 0; j < TN; ++j) wv[j] = Ws[k][n0 + j];
            }
            #pragma unroll
            for (int i = 0; i < TM; ++i)
                #pragma unroll
                for (int j = 0; j < TN; ++j) acc[i][j] = fmaf(av[i], wv[j], acc[i][j]);
        }
        __syncthreads();
    }

    #pragma unroll
    for (int i = 0; i < TM; ++i) {
        const size_t r = (size_t)(row0 + m0 + i);
        #pragma unroll
        for (int j = 0; j < TN; ++j) {
            const int c = col0 + n0 + j;
            float v = acc[i][j];
            if constexpr (NB >= 1) v += b1[c];
            if constexpr (NB >= 2) v += b2[c];
            if constexpr (ACT == 1) v = tanhf(v);
            else if constexpr (ACT == 2) v = 1.0f / (1.0f + expf(-v));
            outp[r * (size_t)N + c] = v;
        }
    }
}

// One recurrence step: hdst = tanh(hsrc @ Wh^T + hdst_staged_xp), all f32.
// Per-step launch (graph-replayed). Block: 512 threads (8 waves), tile
// 16 rows x 32 cols, grid 32x8 = 256 blocks (1/CU, 2 waves/SIMD).
// lane=k mapping: h tile staged coalesced into LDS (64KB), read back as
// consecutive-address ds_read_b128 (conflict-free); Wh streamed straight
// from L2 into registers, fully coalesced; 4x4 register tile -> 16 FMA per
// Wh b128. k folded over 16 lanes via 4 shfl_xor rounds; tiny LDS transpose
// for the epilogue (fused staged-xp add + tanh, same-thread RMW).
__global__ __launch_bounds__(512)
void step_v3(const float* __restrict__ hsrc, const float* __restrict__ Wh,
             float* __restrict__ hdst)
{
    __shared__ float hS[16][1024];   // 64KB
    __shared__ float red[16][33];

    const int tid = threadIdx.x;
    const int c0  = blockIdx.x * 32;
    const int r0  = blockIdx.y * 16;

    // prefetch staged xp for the epilogue (written by xproj GEMM)
    const int ep_r = tid >> 5, ep_c = tid & 31;
    const size_t ep_idx = (size_t)(r0 + ep_r) * H_ + (c0 + ep_c);
    const float xpv = hdst[ep_idx];

    // stage h tile: 16 rows x 1024 floats, fully coalesced
    #pragma unroll
    for (int it = 0; it < 8; ++it) {
        const int chunk = tid + it * 512;          // 4096 float4 chunks
        const int row = chunk >> 8;
        const int k4  = (chunk & 255) * 4;
        *(float4*)&hS[row][k4] =
            *(const float4*)(hsrc + (size_t)(r0 + row) * H_ + k4);
    }
    __syncthreads();

    const int w     = tid >> 6;       // wave 0..7: cols c0 + w*4 .. +3
    const int lane  = tid & 63;
    const int kslot = lane & 15;      // k = kslot*4 + 64*i
    const int rq    = lane >> 4;      // rows rq*4 .. +3

    float acc[4][4];
    #pragma unroll
    for (int r = 0; r < 4; ++r)
        #pragma unroll
        for (int c = 0; c < 4; ++c) acc[r][c] = 0.f;

    const float* whb = Wh + (size_t)(c0 + w * 4) * H_ + kslot * 4;

    #pragma unroll 4
    for (int i = 0; i < 16; ++i) {
        const int k = kslot * 4 + i * 64;
        float4 hv[4];
        #pragma unroll
        for (int r = 0; r < 4; ++r)
            hv[r] = *(const float4*)&hS[rq * 4 + r][k];
        #pragma unroll
        for (int c = 0; c < 4; ++c) {
            const float4 wv = *(const float4*)(whb + (size_t)c * H_ + i * 64);
            #pragma unroll
            for (int r = 0; r < 4; ++r) {
                acc[r][c] = fmaf(hv[r].x, wv.x, acc[r][c]);
                acc[r][c] = fmaf(hv[r].y, wv.y, acc[r][c]);
                acc[r][c] = fmaf(hv[r].z, wv.z, acc[r][c]);
                acc[r][c] = fmaf(hv[r].w, wv.w, acc[r][c]);
            }
        }
    }

    // fold the 16 k-slots (butterfly within 16-lane groups)
    #pragma unroll
    for (int m = 1; m < 16; m <<= 1)
        #pragma unroll
        for (int r = 0; r < 4; ++r)
            #pragma unroll
            for (int c = 0; c < 4; ++c)
                acc[r][c] += __shfl_xor(acc[r][c], m, 64);

    if (kslot == 0) {
        #pragma unroll
        for (int r = 0; r < 4; ++r)
            #pragma unroll
            for (int c = 0; c < 4; ++c)
                red[rq * 4 + r][w * 4 + c] = acc[r][c];
    }
    __syncthreads();

    // epilogue: one cell/thread, fused xp add + tanh, coalesced store
    hdst[ep_idx] = tanhf(red[ep_r][ep_c] + xpv);
}

extern "C" void kernel_launch(void* const* d_in, const int* in_sizes, int n_in,
                              void* d_out, int out_size, void* d_ws, size_t ws_size,
                              hipStream_t stream)
{
    const float* x    = (const float*)d_in[0];
    const float* h0   = (const float*)d_in[1];
    const float* Wx_w = (const float*)d_in[2];
    const float* Wx_b = (const float*)d_in[3];
    const float* Wh_w = (const float*)d_in[4];
    const float* Wh_b = (const float*)d_in[5];
    const float* Wo_w = (const float*)d_in[6];
    const float* Wo_b = (const float*)d_in[7];

    float* out   = (float*)d_out;
    float* all_h = out;                              // [T+1][B][H]
    float* all_y = out + (size_t)(T_ + 1) * BH;      // [T][B][OUT]
    float* last  = all_y + (size_t)T_ * B_ * OUT_;   // [B][OUT]

    // all_h[0] = h0
    copy_h0_kernel<<<dim3((B_*H_ + 255)/256), dim3(256), 0, stream>>>(h0, all_h);

    // Stage xproj = x@Wx^T + Wx_b + Wh_b into all_h[1..T]
    gemm_kernel<128, 128, 16, 8, 8, 2, 0>
        <<<dim3(H_/128, (T_*B_)/128), dim3(256), 0, stream>>>(
            x, Wx_w, Wx_b, Wh_b, all_h + BH, T_*B_, H_, DIM_);

    // Recurrence: per-step launches over the staged slot
    for (int t = 0; t < T_; ++t) {
        step_v3<<<dim3(32, 8), dim3(512), 0, stream>>>(
            all_h + (size_t)t * BH, Wh_w, all_h + (size_t)(t + 1) * BH);
    }

    // all_y = sigmoid(hs @ Wo^T + Wo_b)
    gemm_kernel<128, 128, 16, 8, 8, 1, 2>
        <<<dim3(OUT_/128, (T_*B_)/128), dim3(256), 0, stream>>>(
            all_h + BH, Wo_w, Wo_b, nullptr, all_y, T_*B_, OUT_, H_);

    // last_logits = h_T @ Wo^T + Wo_b
    gemm_kernel<16, 64, 32, 1, 4, 1, 0>
        <<<dim3(OUT_/64, B_/16), dim3(256), 0, stream>>>(
            all_h + (size_t)T_ * BH, Wo_w, Wo_b, nullptr, last, B_, OUT_, H_);
}

// Round 7
// 5507.438 us; speedup vs baseline: 7.8061x; 1.2498x over previous
//
#include <hip/hip_runtime.h>
#include <hip/hip_bf16.h>

static constexpr int T_ = 512, B_ = 128, DIM_ = 512, H_ = 1024, OUT_ = 512;
static constexpr size_t BH = (size_t)B_ * H_;

using short8 = __attribute__((ext_vector_type(8))) short;
using f32x4  = __attribute__((ext_vector_type(4))) float;

__global__ void copy_h0_kernel(const float* __restrict__ h0, float* __restrict__ out) {
    int i = blockIdx.x * blockDim.x + threadIdx.x;
    if (i < B_ * H_) out[i] = h0[i];
}

// ---- bf16 bit helpers (pure bit math, round-to-nearest-even) ----
__device__ __forceinline__ unsigned short f32_to_bf16(float x) {
    unsigned int u = __float_as_uint(x);
    u += 0x7fffu + ((u >> 16) & 1u);
    return (unsigned short)(u >> 16);
}
__device__ __forceinline__ float bf16_to_f32(unsigned short h) {
    return __uint_as_float(((unsigned int)h) << 16);
}

// ================= MFMA GEMM =================
// C[M,N] = act( A[M,K] @ W[N,K]^T + b1 (+ b2) ), A,W f32 in memory.
// SPLIT=0: plain bf16 (1 MFMA/frag);  SPLIT=1: bf16x3 hi/lo (3 MFMA/frag, ~f32 prec)
// Tile 128x128, BK=32, 256 threads (4 waves), wave = 64x64 quadrant, 4x4 frags
// of v_mfma_f32_16x16x32_bf16. LDS: 16B k-units, swizzle unit^=(row>>1)&3.
template<int SPLIT, int NB, int ACT>
__launch_bounds__(256)
__global__ void mfma_gemm(const float* __restrict__ A, const float* __restrict__ W,
                          const float* __restrict__ b1, const float* __restrict__ b2,
                          float* __restrict__ outp, int M, int N, int K)
{
    // each tile: [128 rows][4 units][16B]; hi and (optional) lo planes
    __shared__ unsigned short Ahi[128 * 32], Alo[SPLIT ? 128 * 32 : 1];
    __shared__ unsigned short Bhi[128 * 32], Blo[SPLIT ? 128 * 32 : 1];

    const int tid  = threadIdx.x;
    const int col0 = blockIdx.x * 128;
    const int row0 = blockIdx.y * 128;

    const int wv   = tid >> 6;          // wave 0..3
    const int lane = tid & 63;
    const int wr   = (wv >> 1) * 64;    // wave row offset in tile
    const int wc   = (wv & 1) * 64;     // wave col offset

    f32x4 acc[4][4];
    #pragma unroll
    for (int i = 0; i < 4; ++i)
        #pragma unroll
        for (int j = 0; j < 4; ++j) acc[i][j] = (f32x4){0.f, 0.f, 0.f, 0.f};

    // frag-read shorts offset (in ushort units): row*32 + (unit^((row>>1)&3))*8
    auto frag_off = [](int row, int unit) -> int {
        return row * 32 + ((unit ^ ((row >> 1) & 3)) << 3);
    };

    for (int k0 = 0; k0 < K; k0 += 32) {
        __syncthreads();
        // ---- stage A and B tiles: 1024 float4 chunks each, 256 thr x 4 ----
        #pragma unroll
        for (int i = 0; i < 4; ++i) {
            const int fid = tid + i * 256;       // 0..1023
            const int row = fid >> 3;
            const int f4  = fid & 7;             // float4 index in row (k = f4*4)
            const int unit = f4 >> 1;
            const int uoff = ((unit ^ ((row >> 1) & 3)) << 3) + (f4 & 1) * 4;

            float4 av = *(const float4*)(A + (size_t)(row0 + row) * K + k0 + f4 * 4);
            float4 wvv = *(const float4*)(W + (size_t)(col0 + row) * K + k0 + f4 * 4);

            unsigned short ah[4] = {f32_to_bf16(av.x), f32_to_bf16(av.y),
                                    f32_to_bf16(av.z), f32_to_bf16(av.w)};
            unsigned short bh[4] = {f32_to_bf16(wvv.x), f32_to_bf16(wvv.y),
                                    f32_to_bf16(wvv.z), f32_to_bf16(wvv.w)};
            *(ushort4*)&Ahi[row * 32 + uoff] = make_ushort4(ah[0], ah[1], ah[2], ah[3]);
            *(ushort4*)&Bhi[row * 32 + uoff] = make_ushort4(bh[0], bh[1], bh[2], bh[3]);

            if constexpr (SPLIT) {
                unsigned short al[4] = {
                    f32_to_bf16(av.x - bf16_to_f32(ah[0])),
                    f32_to_bf16(av.y - bf16_to_f32(ah[1])),
                    f32_to_bf16(av.z - bf16_to_f32(ah[2])),
                    f32_to_bf16(av.w - bf16_to_f32(ah[3]))};
                unsigned short bl[4] = {
                    f32_to_bf16(wvv.x - bf16_to_f32(bh[0])),
                    f32_to_bf16(wvv.y - bf16_to_f32(bh[1])),
                    f32_to_bf16(wvv.z - bf16_to_f32(bh[2])),
                    f32_to_bf16(wvv.w - bf16_to_f32(bh[3]))};
                *(ushort4*)&Alo[row * 32 + uoff] = make_ushort4(al[0], al[1], al[2], al[3]);
                *(ushort4*)&Blo[row * 32 + uoff] = make_ushort4(bl[0], bl[1], bl[2], bl[3]);
            }
        }
        __syncthreads();

        // ---- compute: 4x4 frags of 16x16x32 ----
        const int lrow = lane & 15;
        const int unit = lane >> 4;

        short8 bh_f[4], bl_f[4];
        #pragma unroll
        for (int fc = 0; fc < 4; ++fc) {
            bh_f[fc] = *(const short8*)&Bhi[frag_off(wc + fc * 16 + lrow, unit)];
            if constexpr (SPLIT)
                bl_f[fc] = *(const short8*)&Blo[frag_off(wc + fc * 16 + lrow, unit)];
        }
        #pragma unroll
        for (int fr = 0; fr < 4; ++fr) {
            const short8 ah_f = *(const short8*)&Ahi[frag_off(wr + fr * 16 + lrow, unit)];
            if constexpr (SPLIT) {
                const short8 al_f = *(const short8*)&Alo[frag_off(wr + fr * 16 + lrow, unit)];
                #pragma unroll
                for (int fc = 0; fc < 4; ++fc) {
                    acc[fr][fc] = __builtin_amdgcn_mfma_f32_16x16x32_bf16(ah_f, bh_f[fc], acc[fr][fc], 0, 0, 0);
                    acc[fr][fc] = __builtin_amdgcn_mfma_f32_16x16x32_bf16(ah_f, bl_f[fc], acc[fr][fc], 0, 0, 0);
                    acc[fr][fc] = __builtin_amdgcn_mfma_f32_16x16x32_bf16(al_f, bh_f[fc], acc[fr][fc], 0, 0, 0);
                }
            } else {
                #pragma unroll
                for (int fc = 0; fc < 4; ++fc)
                    acc[fr][fc] = __builtin_amdgcn_mfma_f32_16x16x32_bf16(ah_f, bh_f[fc], acc[fr][fc], 0, 0, 0);
            }
        }
    }

    // ---- epilogue: C/D map col=lane&15, row=(lane>>4)*4+j (m91-verified) ----
    const int ccol = lane & 15;
    const int crow = (lane >> 4) * 4;
    #pragma unroll
    for (int fr = 0; fr < 4; ++fr) {
        #pragma unroll
        for (int fc = 0; fc < 4; ++fc) {
            const int col = col0 + wc + fc * 16 + ccol;
            float bias = 0.f;
            if constexpr (NB >= 1) bias += b1[col];
            if constexpr (NB >= 2) bias += b2[col];
            #pragma unroll
            for (int j = 0; j < 4; ++j) {
                const int row = row0 + wr + fr * 16 + crow + j;
                float v = acc[fr][fc][j] + bias;
                if constexpr (ACT == 1) v = tanhf(v);
                else if constexpr (ACT == 2) v = 1.0f / (1.0f + expf(-v));
                outp[(size_t)row * N + col] = v;
            }
        }
    }
}

// ---------------- recurrence step (unchanged from round 6) ----------------
__global__ __launch_bounds__(512)
void step_v3(const float* __restrict__ hsrc, const float* __restrict__ Wh,
             float* __restrict__ hdst)
{
    __shared__ float hS[16][1024];   // 64KB
    __shared__ float red[16][33];

    const int tid = threadIdx.x;
    const int c0  = blockIdx.x * 32;
    const int r0  = blockIdx.y * 16;

    const int ep_r = tid >> 5, ep_c = tid & 31;
    const size_t ep_idx = (size_t)(r0 + ep_r) * H_ + (c0 + ep_c);
    const float xpv = hdst[ep_idx];

    #pragma unroll
    for (int it = 0; it < 8; ++it) {
        const int chunk = tid + it * 512;
        const int row = chunk >> 8;
        const int k4  = (chunk & 255) * 4;
        *(float4*)&hS[row][k4] =
            *(const float4*)(hsrc + (size_t)(r0 + row) * H_ + k4);
    }
    __syncthreads();

    const int w     = tid >> 6;
    const int lane  = tid & 63;
    const int kslot = lane & 15;
    const int rq    = lane >> 4;

    float acc[4][4];
    #pragma unroll
    for (int r = 0; r < 4; ++r)
        #pragma unroll
        for (int c = 0; c < 4; ++c) acc[r][c] = 0.f;

    const float* whb = Wh + (size_t)(c0 + w * 4) * H_ + kslot * 4;

    #pragma unroll 4
    for (int i = 0; i < 16; ++i) {
        const int k = kslot * 4 + i * 64;
        float4 hv[4];
        #pragma unroll
        for (int r = 0; r < 4; ++r)
            hv[r] = *(const float4*)&hS[rq * 4 + r][k];
        #pragma unroll
        for (int c = 0; c < 4; ++c) {
            const float4 wvv = *(const float4*)(whb + (size_t)c * H_ + i * 64);
            #pragma unroll
            for (int r = 0; r < 4; ++r) {
                acc[r][c] = fmaf(hv[r].x, wvv.x, acc[r][c]);
                acc[r][c] = fmaf(hv[r].y, wvv.y, acc[r][c]);
                acc[r][c] = fmaf(hv[r].z, wvv.z, acc[r][c]);
                acc[r][c] = fmaf(hv[r].w, wvv.w, acc[r][c]);
            }
        }
    }

    #pragma unroll
    for (int m = 1; m < 16; m <<= 1)
        #pragma unroll
        for (int r = 0; r < 4; ++r)
            #pragma unroll
            for (int c = 0; c < 4; ++c)
                acc[r][c] += __shfl_xor(acc[r][c], m, 64);

    if (kslot == 0) {
        #pragma unroll
        for (int r = 0; r < 4; ++r)
            #pragma unroll
            for (int c = 0; c < 4; ++c)
                red[rq * 4 + r][w * 4 + c] = acc[r][c];
    }
    __syncthreads();

    hdst[ep_idx] = tanhf(red[ep_r][ep_c] + xpv);
}

extern "C" void kernel_launch(void* const* d_in, const int* in_sizes, int n_in,
                              void* d_out, int out_size, void* d_ws, size_t ws_size,
                              hipStream_t stream)
{
    const float* x    = (const float*)d_in[0];
    const float* h0   = (const float*)d_in[1];
    const float* Wx_w = (const float*)d_in[2];
    const float* Wx_b = (const float*)d_in[3];
    const float* Wh_w = (const float*)d_in[4];
    const float* Wh_b = (const float*)d_in[5];
    const float* Wo_w = (const float*)d_in[6];
    const float* Wo_b = (const float*)d_in[7];

    float* out   = (float*)d_out;
    float* all_h = out;                              // [T+1][B][H]
    float* all_y = out + (size_t)(T_ + 1) * BH;      // [T][B][OUT]
    float* last  = all_y + (size_t)T_ * B_ * OUT_;   // [B][OUT]

    // all_h[0] = h0
    copy_h0_kernel<<<dim3((B_*H_ + 255)/256), dim3(256), 0, stream>>>(h0, all_h);

    // xproj = x@Wx^T + Wx_b + Wh_b  (bf16x3 MFMA, ~f32 precision) -> all_h[1..T]
    mfma_gemm<1, 2, 0><<<dim3(H_/128, (T_*B_)/128), dim3(256), 0, stream>>>(
        x, Wx_w, Wx_b, Wh_b, all_h + BH, T_*B_, H_, DIM_);

    // recurrence (f32 SIMT, unchanged)
    for (int t = 0; t < T_; ++t) {
        step_v3<<<dim3(32, 8), dim3(512), 0, stream>>>(
            all_h + (size_t)t * BH, Wh_w, all_h + (size_t)(t + 1) * BH);
    }

    // all_y = sigmoid(hs @ Wo^T + Wo_b)  (plain bf16 MFMA — downstream of scan)
    mfma_gemm<0, 1, 2><<<dim3(OUT_/128, (T_*B_)/128), dim3(256), 0, stream>>>(
        all_h + BH, Wo_w, Wo_b, nullptr, all_y, T_*B_, OUT_, H_);

    // last_logits = h_T @ Wo^T + Wo_b
    mfma_gemm<0, 1, 0><<<dim3(OUT_/128, 1), dim3(256), 0, stream>>>(
        all_h + (size_t)T_ * BH, Wo_w, Wo_b, nullptr, last, B_, OUT_, H_);
}

// Round 8
// 4838.005 us; speedup vs baseline: 8.8862x; 1.1384x over previous
//
#include <hip/hip_runtime.h>
#include <hip/hip_bf16.h>

static constexpr int T_ = 512, B_ = 128, DIM_ = 512, H_ = 1024, OUT_ = 512;
static constexpr size_t BH = (size_t)B_ * H_;
static constexpr size_t HH = (size_t)H_ * H_;

using short8 = __attribute__((ext_vector_type(8))) short;
using f32x4  = __attribute__((ext_vector_type(4))) float;

// ---- bf16 bit helpers (round-to-nearest-even) ----
__device__ __forceinline__ unsigned short f32_to_bf16(float x) {
    unsigned int u = __float_as_uint(x);
    u += 0x7fffu + ((u >> 16) & 1u);
    return (unsigned short)(u >> 16);
}
__device__ __forceinline__ float bf16_to_f32(unsigned short h) {
    return __uint_as_float(((unsigned int)h) << 16);
}

__global__ void copy_h0_kernel(const float* __restrict__ h0, float* __restrict__ out) {
    int i = blockIdx.x * blockDim.x + threadIdx.x;
    if (i < B_ * H_) out[i] = h0[i];
}

// Convert f32 -> bf16 hi/lo planes (4 elems/thread, vectorized)
__global__ void cvt_planes_kernel(const float* __restrict__ src,
                                  unsigned short* __restrict__ hi,
                                  unsigned short* __restrict__ lo, int n4)
{
    int i = blockIdx.x * blockDim.x + threadIdx.x;
    if (i >= n4) return;
    const float4 v = *(const float4*)(src + (size_t)i * 4);
    unsigned short h[4] = {f32_to_bf16(v.x), f32_to_bf16(v.y),
                           f32_to_bf16(v.z), f32_to_bf16(v.w)};
    unsigned short l[4] = {f32_to_bf16(v.x - bf16_to_f32(h[0])),
                           f32_to_bf16(v.y - bf16_to_f32(h[1])),
                           f32_to_bf16(v.z - bf16_to_f32(h[2])),
                           f32_to_bf16(v.w - bf16_to_f32(h[3]))};
    *(ushort4*)(hi + (size_t)i * 4) = make_ushort4(h[0], h[1], h[2], h[3]);
    *(ushort4*)(lo + (size_t)i * 4) = make_ushort4(l[0], l[1], l[2], l[3]);
}

// ================= MFMA GEMM (unchanged from round 7) =================
template<int SPLIT, int NB, int ACT>
__launch_bounds__(256)
__global__ void mfma_gemm(const float* __restrict__ A, const float* __restrict__ W,
                          const float* __restrict__ b1, const float* __restrict__ b2,
                          float* __restrict__ outp, int M, int N, int K)
{
    __shared__ unsigned short Ahi[128 * 32], Alo[SPLIT ? 128 * 32 : 1];
    __shared__ unsigned short Bhi[128 * 32], Blo[SPLIT ? 128 * 32 : 1];

    const int tid  = threadIdx.x;
    const int col0 = blockIdx.x * 128;
    const int row0 = blockIdx.y * 128;

    const int wv   = tid >> 6;
    const int lane = tid & 63;
    const int wr   = (wv >> 1) * 64;
    const int wc   = (wv & 1) * 64;

    f32x4 acc[4][4];
    #pragma unroll
    for (int i = 0; i < 4; ++i)
        #pragma unroll
        for (int j = 0; j < 4; ++j) acc[i][j] = (f32x4){0.f, 0.f, 0.f, 0.f};

    auto frag_off = [](int row, int unit) -> int {
        return row * 32 + ((unit ^ ((row >> 1) & 3)) << 3);
    };

    for (int k0 = 0; k0 < K; k0 += 32) {
        __syncthreads();
        #pragma unroll
        for (int i = 0; i < 4; ++i) {
            const int fid = tid + i * 256;
            const int row = fid >> 3;
            const int f4  = fid & 7;
            const int unit = f4 >> 1;
            const int uoff = ((unit ^ ((row >> 1) & 3)) << 3) + (f4 & 1) * 4;

            float4 av = *(const float4*)(A + (size_t)(row0 + row) * K + k0 + f4 * 4);
            float4 wvv = *(const float4*)(W + (size_t)(col0 + row) * K + k0 + f4 * 4);

            unsigned short ah[4] = {f32_to_bf16(av.x), f32_to_bf16(av.y),
                                    f32_to_bf16(av.z), f32_to_bf16(av.w)};
            unsigned short bh[4] = {f32_to_bf16(wvv.x), f32_to_bf16(wvv.y),
                                    f32_to_bf16(wvv.z), f32_to_bf16(wvv.w)};
            *(ushort4*)&Ahi[row * 32 + uoff] = make_ushort4(ah[0], ah[1], ah[2], ah[3]);
            *(ushort4*)&Bhi[row * 32 + uoff] = make_ushort4(bh[0], bh[1], bh[2], bh[3]);

            if constexpr (SPLIT) {
                unsigned short al[4] = {
                    f32_to_bf16(av.x - bf16_to_f32(ah[0])),
                    f32_to_bf16(av.y - bf16_to_f32(ah[1])),
                    f32_to_bf16(av.z - bf16_to_f32(ah[2])),
                    f32_to_bf16(av.w - bf16_to_f32(ah[3]))};
                unsigned short bl[4] = {
                    f32_to_bf16(wvv.x - bf16_to_f32(bh[0])),
                    f32_to_bf16(wvv.y - bf16_to_f32(bh[1])),
                    f32_to_bf16(wvv.z - bf16_to_f32(bh[2])),
                    f32_to_bf16(wvv.w - bf16_to_f32(bh[3]))};
                *(ushort4*)&Alo[row * 32 + uoff] = make_ushort4(al[0], al[1], al[2], al[3]);
                *(ushort4*)&Blo[row * 32 + uoff] = make_ushort4(bl[0], bl[1], bl[2], bl[3]);
            }
        }
        __syncthreads();

        const int lrow = lane & 15;
        const int unit = lane >> 4;

        short8 bh_f[4], bl_f[4];
        #pragma unroll
        for (int fc = 0; fc < 4; ++fc) {
            bh_f[fc] = *(const short8*)&Bhi[frag_off(wc + fc * 16 + lrow, unit)];
            if constexpr (SPLIT)
                bl_f[fc] = *(const short8*)&Blo[frag_off(wc + fc * 16 + lrow, unit)];
        }
        #pragma unroll
        for (int fr = 0; fr < 4; ++fr) {
            const short8 ah_f = *(const short8*)&Ahi[frag_off(wr + fr * 16 + lrow, unit)];
            if constexpr (SPLIT) {
                const short8 al_f = *(const short8*)&Alo[frag_off(wr + fr * 16 + lrow, unit)];
                #pragma unroll
                for (int fc = 0; fc < 4; ++fc) {
                    acc[fr][fc] = __builtin_amdgcn_mfma_f32_16x16x32_bf16(ah_f, bh_f[fc], acc[fr][fc], 0, 0, 0);
                    acc[fr][fc] = __builtin_amdgcn_mfma_f32_16x16x32_bf16(ah_f, bl_f[fc], acc[fr][fc], 0, 0, 0);
                    acc[fr][fc] = __builtin_amdgcn_mfma_f32_16x16x32_bf16(al_f, bh_f[fc], acc[fr][fc], 0, 0, 0);
                }
            } else {
                #pragma unroll
                for (int fc = 0; fc < 4; ++fc)
                    acc[fr][fc] = __builtin_amdgcn_mfma_f32_16x16x32_bf16(ah_f, bh_f[fc], acc[fr][fc], 0, 0, 0);
            }
        }
    }

    const int ccol = lane & 15;
    const int crow = (lane >> 4) * 4;
    #pragma unroll
    for (int fr = 0; fr < 4; ++fr) {
        #pragma unroll
        for (int fc = 0; fc < 4; ++fc) {
            const int col = col0 + wc + fc * 16 + ccol;
            float bias = 0.f;
            if constexpr (NB >= 1) bias += b1[col];
            if constexpr (NB >= 2) bias += b2[col];
            #pragma unroll
            for (int j = 0; j < 4; ++j) {
                const int row = row0 + wr + fr * 16 + crow + j;
                float v = acc[fr][fc][j] + bias;
                if constexpr (ACT == 1) v = tanhf(v);
                else if constexpr (ACT == 2) v = 1.0f / (1.0f + expf(-v));
                outp[(size_t)row * N + col] = v;
            }
        }
    }
}

// ============== step_v4: MFMA bf16x4-split recurrence step ==============
// hdst(f32, holds staged xp) = tanh(h @ Wh^T + xp); h given as bf16 hi/lo
// planes, Wh as bf16 hi/lo planes. Writes f32 h to hdst and hi/lo planes
// for the next step. Grid 32x8 (256 blocks, 1/CU), 512 thr = 8 waves
// K-split (128 k each). Block tile 16 rows x 32 cols. Direct global->VGPR
// fragment loads (L2-hot; blockIdx.x%8 gives Wh-col XCD affinity).
__global__ __launch_bounds__(512)
void step_v4(const unsigned short* __restrict__ Phi, const unsigned short* __restrict__ Plo,
             const unsigned short* __restrict__ Whi, const unsigned short* __restrict__ Wlo,
             float* __restrict__ hdst,
             unsigned short* __restrict__ Qhi, unsigned short* __restrict__ Qlo)
{
    __shared__ float red[8][16][33];

    const int tid  = threadIdx.x;
    const int c0   = blockIdx.x * 32;
    const int r0   = blockIdx.y * 16;
    const int w    = tid >> 6;
    const int lane = tid & 63;
    const int lr   = lane & 15;        // frag row/col within 16
    const int kg   = lane >> 4;        // k-group (8 elems each)

    // prefetch staged xp (same-thread RMW)
    const int ep_r = tid >> 5, ep_c = tid & 31;
    const size_t ep_idx = (size_t)(r0 + ep_r) * H_ + (c0 + ep_c);
    const float xpv = hdst[ep_idx];

    const int kbase = w * 128 + kg * 8;
    const unsigned short* pah = Phi + (size_t)(r0 + lr) * H_ + kbase;
    const unsigned short* pal = Plo + (size_t)(r0 + lr) * H_ + kbase;
    const unsigned short* pb0h = Whi + (size_t)(c0 + lr) * H_ + kbase;
    const unsigned short* pb0l = Wlo + (size_t)(c0 + lr) * H_ + kbase;
    const unsigned short* pb1h = Whi + (size_t)(c0 + 16 + lr) * H_ + kbase;
    const unsigned short* pb1l = Wlo + (size_t)(c0 + 16 + lr) * H_ + kbase;

    f32x4 acc0 = {0.f, 0.f, 0.f, 0.f}, acc1 = {0.f, 0.f, 0.f, 0.f};

    #pragma unroll
    for (int it = 0; it < 4; ++it) {
        const int ko = it * 32;
        const short8 ah  = *(const short8*)(pah + ko);
        const short8 al  = *(const short8*)(pal + ko);
        const short8 b0h = *(const short8*)(pb0h + ko);
        const short8 b0l = *(const short8*)(pb0l + ko);
        const short8 b1h = *(const short8*)(pb1h + ko);
        const short8 b1l = *(const short8*)(pb1l + ko);

        acc0 = __builtin_amdgcn_mfma_f32_16x16x32_bf16(ah, b0h, acc0, 0, 0, 0);
        acc0 = __builtin_amdgcn_mfma_f32_16x16x32_bf16(ah, b0l, acc0, 0, 0, 0);
        acc0 = __builtin_amdgcn_mfma_f32_16x16x32_bf16(al, b0h, acc0, 0, 0, 0);
        acc0 = __builtin_amdgcn_mfma_f32_16x16x32_bf16(al, b0l, acc0, 0, 0, 0);
        acc1 = __builtin_amdgcn_mfma_f32_16x16x32_bf16(ah, b1h, acc1, 0, 0, 0);
        acc1 = __builtin_amdgcn_mfma_f32_16x16x32_bf16(ah, b1l, acc1, 0, 0, 0);
        acc1 = __builtin_amdgcn_mfma_f32_16x16x32_bf16(al, b1h, acc1, 0, 0, 0);
        acc1 = __builtin_amdgcn_mfma_f32_16x16x32_bf16(al, b1l, acc1, 0, 0, 0);
    }

    // partials -> LDS (C/D map: row = kg*4+j, col = lr | 16+lr)
    #pragma unroll
    for (int j = 0; j < 4; ++j) {
        red[w][kg * 4 + j][lr]      = acc0[j];
        red[w][kg * 4 + j][16 + lr] = acc1[j];
    }
    __syncthreads();

    // final: one cell per thread
    float s = ((red[0][ep_r][ep_c] + red[1][ep_r][ep_c])
             + (red[2][ep_r][ep_c] + red[3][ep_r][ep_c]))
            + ((red[4][ep_r][ep_c] + red[5][ep_r][ep_c])
             + (red[6][ep_r][ep_c] + red[7][ep_r][ep_c]));
    const float v = tanhf(s + xpv);
    hdst[ep_idx] = v;
    const unsigned short hi = f32_to_bf16(v);
    Qhi[ep_idx] = hi;
    Qlo[ep_idx] = f32_to_bf16(v - bf16_to_f32(hi));
}

// ---------------- step_v3 fallback (unchanged from round 6) ----------------
__global__ __launch_bounds__(512)
void step_v3(const float* __restrict__ hsrc, const float* __restrict__ Wh,
             float* __restrict__ hdst)
{
    __shared__ float hS[16][1024];
    __shared__ float red[16][33];

    const int tid = threadIdx.x;
    const int c0  = blockIdx.x * 32;
    const int r0  = blockIdx.y * 16;

    const int ep_r = tid >> 5, ep_c = tid & 31;
    const size_t ep_idx = (size_t)(r0 + ep_r) * H_ + (c0 + ep_c);
    const float xpv = hdst[ep_idx];

    #pragma unroll
    for (int it = 0; it < 8; ++it) {
        const int chunk = tid + it * 512;
        const int row = chunk >> 8;
        const int k4  = (chunk & 255) * 4;
        *(float4*)&hS[row][k4] =
            *(const float4*)(hsrc + (size_t)(r0 + row) * H_ + k4);
    }
    __syncthreads();

    const int w     = tid >> 6;
    const int lane  = tid & 63;
    const int kslot = lane & 15;
    const int rq    = lane >> 4;

    float acc[4][4];
    #pragma unroll
    for (int r = 0; r < 4; ++r)
        #pragma unroll
        for (int c = 0; c < 4; ++c) acc[r][c] = 0.f;

    const float* whb = Wh + (size_t)(c0 + w * 4) * H_ + kslot * 4;

    #pragma unroll 4
    for (int i = 0; i < 16; ++i) {
        const int k = kslot * 4 + i * 64;
        float4 hv[4];
        #pragma unroll
        for (int r = 0; r < 4; ++r)
            hv[r] = *(const float4*)&hS[rq * 4 + r][k];
        #pragma unroll
        for (int c = 0; c < 4; ++c) {
            const float4 wvv = *(const float4*)(whb + (size_t)c * H_ + i * 64);
            #pragma unroll
            for (int r = 0; r < 4; ++r) {
                acc[r][c] = fmaf(hv[r].x, wvv.x, acc[r][c]);
                acc[r][c] = fmaf(hv[r].y, wvv.y, acc[r][c]);
                acc[r][c] = fmaf(hv[r].z, wvv.z, acc[r][c]);
                acc[r][c] = fmaf(hv[r].w, wvv.w, acc[r][c]);
            }
        }
    }

    #pragma unroll
    for (int m = 1; m < 16; m <<= 1)
        #pragma unroll
        for (int r = 0; r < 4; ++r)
            #pragma unroll
            for (int c = 0; c < 4; ++c)
                acc[r][c] += __shfl_xor(acc[r][c], m, 64);

    if (kslot == 0) {
        #pragma unroll
        for (int r = 0; r < 4; ++r)
            #pragma unroll
            for (int c = 0; c < 4; ++c)
                red[rq * 4 + r][w * 4 + c] = acc[r][c];
    }
    __syncthreads();

    hdst[ep_idx] = tanhf(red[ep_r][ep_c] + xpv);
}

extern "C" void kernel_launch(void* const* d_in, const int* in_sizes, int n_in,
                              void* d_out, int out_size, void* d_ws, size_t ws_size,
                              hipStream_t stream)
{
    const float* x    = (const float*)d_in[0];
    const float* h0   = (const float*)d_in[1];
    const float* Wx_w = (const float*)d_in[2];
    const float* Wx_b = (const float*)d_in[3];
    const float* Wh_w = (const float*)d_in[4];
    const float* Wh_b = (const float*)d_in[5];
    const float* Wo_w = (const float*)d_in[6];
    const float* Wo_b = (const float*)d_in[7];

    float* out   = (float*)d_out;
    float* all_h = out;                              // [T+1][B][H]
    float* all_y = out + (size_t)(T_ + 1) * BH;      // [T][B][OUT]
    float* last  = all_y + (size_t)T_ * B_ * OUT_;   // [B][OUT]

    // all_h[0] = h0
    copy_h0_kernel<<<dim3((B_*H_ + 255)/256), dim3(256), 0, stream>>>(h0, all_h);

    // xproj = x@Wx^T + Wx_b + Wh_b (bf16x3 MFMA) -> staged into all_h[1..T]
    mfma_gemm<1, 2, 0><<<dim3(H_/128, (T_*B_)/128), dim3(256), 0, stream>>>(
        x, Wx_w, Wx_b, Wh_b, all_h + BH, T_*B_, H_, DIM_);

    // ---- recurrence ----
    const size_t need_ws = (2 * HH + 4 * BH) * sizeof(unsigned short);
    if (ws_size >= need_ws) {
        unsigned short* wsu = (unsigned short*)d_ws;
        unsigned short* Whi = wsu;
        unsigned short* Wlo = wsu + HH;
        unsigned short* P0h = wsu + 2 * HH;
        unsigned short* P0l = P0h + BH;
        unsigned short* P1h = P0l + BH;
        unsigned short* P1l = P1h + BH;

        // Wh -> hi/lo planes (once); h0 -> plane 0
        cvt_planes_kernel<<<dim3((int)(HH/4/256)), dim3(256), 0, stream>>>(
            Wh_w, Whi, Wlo, (int)(HH/4));
        cvt_planes_kernel<<<dim3((int)(BH/4/256)), dim3(256), 0, stream>>>(
            h0, P0h, P0l, (int)(BH/4));

        for (int t = 0; t < T_; ++t) {
            unsigned short* ph = (t & 1) ? P1h : P0h;
            unsigned short* pl = (t & 1) ? P1l : P0l;
            unsigned short* qh = (t & 1) ? P0h : P1h;
            unsigned short* ql = (t & 1) ? P0l : P1l;
            step_v4<<<dim3(32, 8), dim3(512), 0, stream>>>(
                ph, pl, Whi, Wlo, all_h + (size_t)(t + 1) * BH, qh, ql);
        }
    } else {
        for (int t = 0; t < T_; ++t) {
            step_v3<<<dim3(32, 8), dim3(512), 0, stream>>>(
                all_h + (size_t)t * BH, Wh_w, all_h + (size_t)(t + 1) * BH);
        }
    }

    // all_y = sigmoid(hs @ Wo^T + Wo_b)  (plain bf16 MFMA — downstream of scan)
    mfma_gemm<0, 1, 2><<<dim3(OUT_/128, (T_*B_)/128), dim3(256), 0, stream>>>(
        all_h + BH, Wo_w, Wo_b, nullptr, all_y, T_*B_, OUT_, H_);

    // last_logits = h_T @ Wo^T + Wo_b
    mfma_gemm<0, 1, 0><<<dim3(OUT_/128, 1), dim3(256), 0, stream>>>(
        all_h + (size_t)T_ * BH, Wo_w, Wo_b, nullptr, last, B_, OUT_, H_);
}